// Round 13
// baseline (230.746 us; speedup 1.0000x reference)
//
#include <hip/hip_runtime.h>

#define NLINKS 4096
#define THREADS 512
#define CHUNKS 2          // fvec4 per thread: 2 * 4 * 512 threads = 4096 elems
#define NWAVES 8

typedef float fvec4 __attribute__((ext_vector_type(4)));

constexpr float kPmax = 0.1f;
constexpr float kBudget = 100.0f;
constexpr int kGrid = 5;          // tau grid points evaluated in pass A
constexpr float kBmax = 16.0f;    // constant upper bracket: g(16)=0 always
constexpr int kFallbackIters = 8; // Illinois iters when tau is outside grid

// clip(x,0,PMAX) in ONE VALU op: v_med3_f32
__device__ __forceinline__ float clip01(float x) {
  return __builtin_amdgcn_fmed3f(x, 0.0f, kPmax);
}

// Batched reduce: N independent sums share interleaved shuffle latency.
template <int N>
__device__ __forceinline__ void waveReduceSumN(float* x) {
#pragma unroll
  for (int m = 32; m >= 1; m >>= 1) {
    float t[N];
#pragma unroll
    for (int k = 0; k < N; ++k) t[k] = __shfl_xor(x[k], m, 64);
#pragma unroll
    for (int k = 0; k < N; ++k) x[k] += t[k];
  }
}

// ROUNDS 0-12 LESSON LEDGER (falsified as the bottleneck):
//  r1/r2: register pressure (dbuf always spills at 128-VGPR cap)
//  r3/r4: wait placement (counted vmcnt: no change)
//  r6:    occupancy (3x more waves: no change)
//  r8:    VALU volume (-35% pass-A ops: no change)
//  r9:    load-latency exposure (verified in-flight prefetch: no change)
//  r10:   phase heterogeneity (kernel split: WORSE by ~25 us)
//  r11/r12 (2x2 complete): store policy irrelevant (plain/plain==plain/NT);
//         LOAD policy worth ~8 us and NT WINS despite 2x HBM fetch — the
//         L3-hit read path is slower than HBM-direct NT streaming here.
//         Best: NT loads + NT stores, block-per-row (r8, bench ~221).
//  SURVIVING TREND: elems/thread. 64/thr (r0) = 226.8; 16/thr (r8) = 220.9.
//  Shorter per-thread serial chains -> earlier barrier arrival -> earlier
//  stores -> better cross-block pipelining. THIS ROUND probes the next
//  point: 512-thread blocks, 8 elems/thread, single variable vs r8.
//  If >223: geometry saturated; revert to r8 and declare the ceiling.
__global__ __launch_bounds__(THREADS) void proj_kernel(
    const float* __restrict__ raw, float* __restrict__ out, int rows) {
  const int row = blockIdx.x;
  if (row >= rows) return;
  const int tid = threadIdx.x;
  const int wave = tid >> 6;
  const int lane = tid & 63;

  // Site-private LDS so reduce sites can't race each other.
  __shared__ float ldsA[NWAVES][kGrid + 1];  // pass A: s[0..kGrid]
  __shared__ float ldsF[NWAVES];             // fallback g (rare)
  __shared__ float ldsN[NWAVES][2];          // Newton: g(tau0), n_active

  const fvec4* rp = (const fvec4*)(raw + (size_t)row * NLINKS);
  fvec4* op = (fvec4*)(out + (size_t)row * NLINKS);

  // Whole row in block registers: 2 fvec4/thread = 8 VGPRs, coalesced.
  // NT loads: measured best (r8 vs r11/r12 — HBM-direct beats L3-hit path).
  fvec4 v[CHUNKS];
#pragma unroll
  for (int j = 0; j < CHUNKS; ++j)
    v[j] = __builtin_nontemporal_load(&rp[tid + THREADS * j]);

  // tau ~= 0.641 +- 0.02 (sigma across rows) for this problem's N(0,1)
  // inputs; points span +-5 sigma. Outside -> Illinois fallback (correct).
  const float pts[kGrid] = {0.54f, 0.60f, 0.65f, 0.70f, 0.76f};

  // ---- Pass A: g(0)=fs and g(pts[i]) for all grid points ----
  float s[kGrid + 1];
#pragma unroll
  for (int k = 0; k <= kGrid; ++k) s[k] = 0.f;
#pragma unroll
  for (int j = 0; j < CHUNKS; ++j) {
#pragma unroll
    for (int c = 0; c < 4; ++c) {
      const float x = v[j][c];
      s[0] += clip01(x);
#pragma unroll
      for (int i = 0; i < kGrid; ++i) s[i + 1] += clip01(x - pts[i]);
    }
  }
  waveReduceSumN<kGrid + 1>(s);
  if (lane == 0) {
#pragma unroll
    for (int k = 0; k <= kGrid; ++k) ldsA[wave][k] = s[k];
  }
  __syncthreads();
#pragma unroll
  for (int k = 0; k <= kGrid; ++k)
    s[k] = ((ldsA[0][k] + ldsA[1][k]) + (ldsA[2][k] + ldsA[3][k])) +
           ((ldsA[4][k] + ldsA[5][k]) + (ldsA[6][k] + ldsA[7][k]));
  const float fs = s[0];

  if (fs <= kBudget) {  // feasible: clip only (block-uniform branch)
#pragma unroll
    for (int j = 0; j < CHUNKS; ++j) {
      fvec4 o;
#pragma unroll
      for (int c = 0; c < 4; ++c) o[c] = clip01(v[j][c]);
      __builtin_nontemporal_store(o, &op[tid + THREADS * j]);
    }
    return;
  }

  // Select bracketing segment. g is decreasing: g(0)=fs>B, g(kBmax)=0.
  float a = 0.f, ga = fs, b = kBmax, gb = 0.f;
  bool need_iter = true;
  if (s[1] < kBudget) {                    // tau < pts[0]: Illinois refines
    a = 0.f; ga = fs; b = pts[0]; gb = s[1];
  } else if (s[kGrid] > kBudget) {         // tau > pts[last]: Illinois refines
    a = pts[kGrid - 1]; ga = s[kGrid]; b = kBmax; gb = 0.f;
  } else {
#pragma unroll
    for (int i = 0; i < kGrid - 1; ++i) {
      if (s[i + 1] >= kBudget && s[i + 2] <= kBudget) {
        a = pts[i]; ga = s[i + 1]; b = pts[i + 1]; gb = s[i + 2];
        need_iter = false;
        break;
      }
    }
  }

  if (need_iter) {  // rare: Illinois false position on [a,b] (block-uniform)
    int side = 0;
#pragma unroll 1
    for (int it = 0; it < kFallbackIters; ++it) {
      const float denom = gb - ga;
      float t = (denom != 0.f) ? b - (gb - kBudget) * (b - a) / denom
                               : 0.5f * (a + b);
      if (!(t > a && t < b)) t = 0.5f * (a + b);
      float s0 = 0.f, s1 = 0.f;
#pragma unroll
      for (int j = 0; j < CHUNKS; ++j) {
        s0 += clip01(v[j].x - t) + clip01(v[j].z - t);
        s1 += clip01(v[j].y - t) + clip01(v[j].w - t);
      }
      float g = s0 + s1;
      waveReduceSumN<1>(&g);
      if (lane == 0) ldsF[wave] = g;
      __syncthreads();
      g = ((ldsF[0] + ldsF[1]) + (ldsF[2] + ldsF[3])) +
          ((ldsF[4] + ldsF[5]) + (ldsF[6] + ldsF[7]));
      __syncthreads();  // ldsF rewritten next iteration
      if (g > kBudget) {
        a = t; ga = g;
        if (side == 1) gb = kBudget + 0.5f * (gb - kBudget);
        side = 1;
      } else {
        b = t; gb = g;
        if (side == -1) ga = kBudget + 0.5f * (ga - kBudget);
        side = -1;
      }
    }
  }

  // False position within the (locally linear) segment.
  const float dd = ga - gb;
  float tau0 = (dd != 0.f) ? a + (ga - kBudget) * (b - a) / dd : 0.5f * (a + b);
  if (!(tau0 >= a && tau0 <= b)) tau0 = 0.5f * (a + b);

  // ---- Pass B: Newton correction (exact within the linear segment) ----
  float gn[2] = {0.f, 0.f};  // gn[0]=g(tau0), gn[1]=n_active
#pragma unroll
  for (int j = 0; j < CHUNKS; ++j) {
#pragma unroll
    for (int c = 0; c < 4; ++c) {
      const float t = v[j][c] - tau0;
      gn[0] += clip01(t);
      gn[1] += (t > 0.f && t < kPmax) ? 1.f : 0.f;
    }
  }
  waveReduceSumN<2>(gn);
  if (lane == 0) {
    ldsN[wave][0] = gn[0];
    ldsN[wave][1] = gn[1];
  }
  __syncthreads();
  gn[0] = ((ldsN[0][0] + ldsN[1][0]) + (ldsN[2][0] + ldsN[3][0])) +
          ((ldsN[4][0] + ldsN[5][0]) + (ldsN[6][0] + ldsN[7][0]));
  gn[1] = ((ldsN[0][1] + ldsN[1][1]) + (ldsN[2][1] + ldsN[3][1])) +
          ((ldsN[4][1] + ldsN[5][1]) + (ldsN[6][1] + ldsN[7][1]));
  const float tau = tau0 + (gn[0] - kBudget) / fmaxf(gn[1], 1.0f);

  // ---- Pass C: output from registers (NT stores) ----
#pragma unroll
  for (int j = 0; j < CHUNKS; ++j) {
    fvec4 o;
#pragma unroll
    for (int c = 0; c < 4; ++c) o[c] = clip01(v[j][c] - tau);
    __builtin_nontemporal_store(o, &op[tid + THREADS * j]);
  }
}

extern "C" void kernel_launch(void* const* d_in, const int* in_sizes, int n_in,
                              void* d_out, int out_size, void* d_ws, size_t ws_size,
                              hipStream_t stream) {
  const float* raw = (const float*)d_in[0];
  float* out = (float*)d_out;
  const int rows = in_sizes[0] / NLINKS;
  // One row per 512-thread block: 8 elems/thread — next point on the
  // (elems/thread -> time) curve after 64 (226.8) and 16 (220.9).
  hipLaunchKernelGGL(proj_kernel, dim3(rows), dim3(THREADS), 0, stream,
                     raw, out, rows);
}

// Round 14
// 220.081 us; speedup vs baseline: 1.0485x; 1.0485x over previous
//
#include <hip/hip_runtime.h>

#define NLINKS 4096
#define CHUNKS 4          // fvec4 per thread: 4 * 4 * 256 threads = 4096 elems

typedef float fvec4 __attribute__((ext_vector_type(4)));

constexpr float kPmax = 0.1f;
constexpr float kBudget = 100.0f;
constexpr int kGrid = 5;          // tau grid points evaluated in pass A
constexpr float kBmax = 16.0f;    // constant upper bracket: g(16)=0 always
constexpr int kFallbackIters = 8; // Illinois iters when tau is outside grid

// clip(x,0,PMAX) in ONE VALU op: v_med3_f32
__device__ __forceinline__ float clip01(float x) {
  return __builtin_amdgcn_fmed3f(x, 0.0f, kPmax);
}

// Batched reduce: N independent sums share interleaved shuffle latency.
template <int N>
__device__ __forceinline__ void waveReduceSumN(float* x) {
#pragma unroll
  for (int m = 32; m >= 1; m >>= 1) {
    float t[N];
#pragma unroll
    for (int k = 0; k < N; ++k) t[k] = __shfl_xor(x[k], m, 64);
#pragma unroll
    for (int k = 0; k < N; ++k) x[k] += t[k];
  }
}

// FINAL KERNEL — exact revert to the round-8 configuration, the measured
// minimum of the explored space (bench 220.9 us; proj ~63 us = 4.25 TB/s
// on 268 MB vs the 42.6 us pure-traffic floor).
//
// FULL FALSIFICATION LEDGER (rounds 0-13, all single-variable where possible):
//  r1/r2: register double-buffer -> allocator pins 128 VGPRs, always spills.
//  r3/r4: LDS prefetch + counted vmcnt -> no change (store drain not the cost).
//  r6:    occupancy 3x (27.6%) at VGPR 76 -> no change.
//  r7:    block-per-row (16 elems/thr) -> ~70 us. THE structural win.
//  r8:    pass-A VALU -35% -> no change (VALU off critical path). Best: 220.9.
//  r9:    within-block row pipelining, non-draining barriers -> no change.
//  r10:   two homogeneous kernels (tau+apply) -> WORSE by ~25 us.
//  r11/r12: cache-policy 2x2: store policy irrelevant; NT loads BEAT plain
//         loads by ~8 us despite 2x HBM fetch (L3-hit read path slower than
//         HBM-direct NT streaming for this pattern).
//  r13:   512-thr/8-elems geometry -> WORSE (230.7). elems/thread curve is
//         U-shaped: 64->226.8, 16->220.9, 8->230.7. Optimum = 16.
// Residual ~20 us above the traffic floor: no saturated counter (VALUBusy
// ~30%, HBM ~31%, occupancy ~50%); every scheduling/caching/geometry lever
// falsified. Declared plateau for this access shape (burst read -> barrier-
// synced row reduce -> burst write, 16 KB per block).
__global__ __launch_bounds__(256) void proj_kernel(
    const float* __restrict__ raw, float* __restrict__ out, int rows) {
  const int row = blockIdx.x;
  if (row >= rows) return;
  const int tid = threadIdx.x;
  const int wave = tid >> 6;
  const int lane = tid & 63;

  // Site-private LDS so reduce sites can't race each other.
  __shared__ float ldsA[4][kGrid + 1];  // pass A: s[0..kGrid]
  __shared__ float ldsF[4];             // fallback g (rewritten per iter)
  __shared__ float ldsN[4][2];          // Newton: g(tau0), n_active

  const fvec4* rp = (const fvec4*)(raw + (size_t)row * NLINKS);
  fvec4* op = (fvec4*)(out + (size_t)row * NLINKS);

  // Whole row in block registers: 4 fvec4/thread = 16 VGPRs, coalesced.
  // NT loads: measured best (r11/r12 A/B) — HBM-direct beats the L3 path.
  fvec4 v[CHUNKS];
#pragma unroll
  for (int j = 0; j < CHUNKS; ++j)
    v[j] = __builtin_nontemporal_load(&rp[tid + 256 * j]);

  // tau ~= 0.641 +- 0.02 (sigma across rows) for this problem's N(0,1)
  // inputs; points span +-5 sigma. Outside -> Illinois fallback (correct).
  const float pts[kGrid] = {0.54f, 0.60f, 0.65f, 0.70f, 0.76f};

  // ---- Pass A: g(0)=fs and g(pts[i]) for all grid points ----
  float s[kGrid + 1];
#pragma unroll
  for (int k = 0; k <= kGrid; ++k) s[k] = 0.f;
#pragma unroll
  for (int j = 0; j < CHUNKS; ++j) {
#pragma unroll
    for (int c = 0; c < 4; ++c) {
      const float x = v[j][c];
      s[0] += clip01(x);
#pragma unroll
      for (int i = 0; i < kGrid; ++i) s[i + 1] += clip01(x - pts[i]);
    }
  }
  waveReduceSumN<kGrid + 1>(s);
  if (lane == 0) {
#pragma unroll
    for (int k = 0; k <= kGrid; ++k) ldsA[wave][k] = s[k];
  }
  __syncthreads();
#pragma unroll
  for (int k = 0; k <= kGrid; ++k)
    s[k] = (ldsA[0][k] + ldsA[1][k]) + (ldsA[2][k] + ldsA[3][k]);
  const float fs = s[0];

  if (fs <= kBudget) {  // feasible: clip only (block-uniform branch)
#pragma unroll
    for (int j = 0; j < CHUNKS; ++j) {
      fvec4 o;
#pragma unroll
      for (int c = 0; c < 4; ++c) o[c] = clip01(v[j][c]);
      __builtin_nontemporal_store(o, &op[tid + 256 * j]);
    }
    return;
  }

  // Select bracketing segment. g is decreasing: g(0)=fs>B, g(kBmax)=0.
  float a = 0.f, ga = fs, b = kBmax, gb = 0.f;
  bool need_iter = true;
  if (s[1] < kBudget) {                    // tau < pts[0]: Illinois refines
    a = 0.f; ga = fs; b = pts[0]; gb = s[1];
  } else if (s[kGrid] > kBudget) {         // tau > pts[last]: Illinois refines
    a = pts[kGrid - 1]; ga = s[kGrid]; b = kBmax; gb = 0.f;
  } else {
#pragma unroll
    for (int i = 0; i < kGrid - 1; ++i) {
      if (s[i + 1] >= kBudget && s[i + 2] <= kBudget) {
        a = pts[i]; ga = s[i + 1]; b = pts[i + 1]; gb = s[i + 2];
        need_iter = false;
        break;
      }
    }
  }

  if (need_iter) {  // rare: Illinois false position on [a,b] (block-uniform)
    int side = 0;
#pragma unroll 1
    for (int it = 0; it < kFallbackIters; ++it) {
      const float denom = gb - ga;
      float t = (denom != 0.f) ? b - (gb - kBudget) * (b - a) / denom
                               : 0.5f * (a + b);
      if (!(t > a && t < b)) t = 0.5f * (a + b);
      float s0 = 0.f, s1 = 0.f, s2 = 0.f, s3 = 0.f;
#pragma unroll
      for (int j = 0; j < CHUNKS; ++j) {
        s0 += clip01(v[j].x - t);
        s1 += clip01(v[j].y - t);
        s2 += clip01(v[j].z - t);
        s3 += clip01(v[j].w - t);
      }
      float g = (s0 + s1) + (s2 + s3);
      waveReduceSumN<1>(&g);
      if (lane == 0) ldsF[wave] = g;
      __syncthreads();
      g = (ldsF[0] + ldsF[1]) + (ldsF[2] + ldsF[3]);
      __syncthreads();  // ldsF rewritten next iteration
      if (g > kBudget) {
        a = t; ga = g;
        if (side == 1) gb = kBudget + 0.5f * (gb - kBudget);
        side = 1;
      } else {
        b = t; gb = g;
        if (side == -1) ga = kBudget + 0.5f * (ga - kBudget);
        side = -1;
      }
    }
  }

  // False position within the (locally linear) segment.
  const float dd = ga - gb;
  float tau0 = (dd != 0.f) ? a + (ga - kBudget) * (b - a) / dd : 0.5f * (a + b);
  if (!(tau0 >= a && tau0 <= b)) tau0 = 0.5f * (a + b);

  // ---- Pass B: Newton correction (exact within the linear segment) ----
  float gn[2] = {0.f, 0.f};  // gn[0]=g(tau0), gn[1]=n_active
#pragma unroll
  for (int j = 0; j < CHUNKS; ++j) {
#pragma unroll
    for (int c = 0; c < 4; ++c) {
      const float t = v[j][c] - tau0;
      gn[0] += clip01(t);
      gn[1] += (t > 0.f && t < kPmax) ? 1.f : 0.f;
    }
  }
  waveReduceSumN<2>(gn);
  if (lane == 0) {
    ldsN[wave][0] = gn[0];
    ldsN[wave][1] = gn[1];
  }
  __syncthreads();
  gn[0] = (ldsN[0][0] + ldsN[1][0]) + (ldsN[2][0] + ldsN[3][0]);
  gn[1] = (ldsN[0][1] + ldsN[1][1]) + (ldsN[2][1] + ldsN[3][1]);
  const float tau = tau0 + (gn[0] - kBudget) / fmaxf(gn[1], 1.0f);

  // ---- Pass C: output from registers (NT stores) ----
#pragma unroll
  for (int j = 0; j < CHUNKS; ++j) {
    fvec4 o;
#pragma unroll
    for (int c = 0; c < 4; ++c) o[c] = clip01(v[j][c] - tau);
    __builtin_nontemporal_store(o, &op[tid + 256 * j]);
  }
}

extern "C" void kernel_launch(void* const* d_in, const int* in_sizes, int n_in,
                              void* d_out, int out_size, void* d_ws, size_t ws_size,
                              hipStream_t stream) {
  const float* raw = (const float*)d_in[0];
  float* out = (float*)d_out;
  const int rows = in_sizes[0] / NLINKS;
  // One row per 256-thread block, 16 elems/thread: measured optimum of the
  // elems/thread curve (64->226.8, 16->220.9, 8->230.7).
  hipLaunchKernelGGL(proj_kernel, dim3(rows), dim3(256), 0, stream,
                     raw, out, rows);
}